// Round 7
// baseline (532.663 us; speedup 1.0000x reference)
//
#include <hip/hip_runtime.h>
#include <math.h>

#define BB 8
#define PP 57744
#define NOBJ 20
#define CC 81
#define ROWS (BB*PP)
#define RPB 64        // rows per block in k_main (round-0 proven structure)
#define BPSPLIT 16
#define BPCHUNK ((PP + BPSPLIT - 1) / BPSPLIT)   // 3609
#define SELBLK 128    // k_sel blocks — tiny grid: per-thread work still <4 uint4

// ws layout in 4-byte units
// cnt: [0]=num_pos [1]=sl1_sum(f) [2]=pos_ce(f) [3]=neg_ce(f) [4]=neg_cnt
//      [5]=eqCtr [6]=doneA [7]=skip [8]=prefixA [9]=KrB [10]=T [11]=eqSlots
//      [12]=doneB [13]=doneD [14]=flagB [15]=prefixAB [16]=KrC [17]=doneC
//      [20]=flagA [21]=flagD
#define W_CNT  0
#define W_BP   64                      // 160 u64 (byte 256, 8-aligned)
#define W_HA   1024                    // 4 copies x 2048 bins
#define W_HB   (W_HA + 4*2048)         // 4 copies x 2048
#define W_HC   (W_HB + 4*2048)         // 4 copies x 1024
#define W_KEY  (W_HC + 4*1024)         // ROWS uints
#define W_CE   (W_KEY + ROWS)          // ROWS floats
#define MEMSET_BYTES (W_KEY * 4)       // 86016 B: counters + bp + hists

#define SCOPE_AGENT __HIP_MEMORY_SCOPE_AGENT
// Completion (not fence) ordering: all prior vmem ops (incl. non-returning
// atomics) retired at the coherence point before anything after this line.
// Deliberately NOT __threadfence(): no buffer_wbl2 / buffer_inv emitted.
#define VMEM_DRAIN() asm volatile("s_waitcnt vmcnt(0) lgkmcnt(0)" ::: "memory")

__device__ __forceinline__ unsigned keymap(float f) {
    unsigned u = __float_as_uint(f);
    return (u & 0x80000000u) ? ~u : (u | 0x80000000u);
}

__device__ __forceinline__ float smooth_l1(float d) {
    float a = fabsf(d);
    return a < 1.f ? 0.5f * d * d : a - 0.5f;
}

__device__ __forceinline__ unsigned aload_u(const unsigned* p) {
    return __hip_atomic_load(p, __ATOMIC_RELAXED, SCOPE_AGENT);
}
__device__ __forceinline__ int aload_i(const int* p) {
    return __hip_atomic_load(p, __ATOMIC_RELAXED, SCOPE_AGENT);
}
__device__ __forceinline__ float aload_f(const float* p) {
    return __hip_atomic_load(p, __ATOMIC_RELAXED, SCOPE_AGENT);
}
__device__ __forceinline__ void astore_i(int* p, int v) {
    __hip_atomic_store(p, v, __ATOMIC_RELAXED, SCOPE_AGENT);
}

// Descending-cumulative threshold search over NB bins summed across NC global
// copies (relaxed agent loads). Finds bin B with suffix(B) >= Kr &&
// suffix(B+1) < Kr; *rem_out = Kr - suffix(B+1). Returns -1 if total < Kr.
template <int NB, int NC>
__device__ int scan_bins(const unsigned* h, unsigned Kr, unsigned* rem_out) {
    constexpr int BPT = NB / 256;
    __shared__ unsigned stot[256];
    __shared__ int sbin;
    __shared__ unsigned srem;
    int i = threadIdx.x;
    unsigned v[BPT];
    unsigned tot = 0;
    #pragma unroll
    for (int j = 0; j < BPT; j++) {
        unsigned s = 0;
        #pragma unroll
        for (int c = 0; c < NC; c++) s += aload_u(h + c * NB + i * BPT + j);
        v[j] = s; tot += s;
    }
    if (i == 0) sbin = -1;
    stot[i] = tot; __syncthreads();
    for (int off = 1; off < 256; off <<= 1) {   // inclusive suffix scan
        unsigned add = (i + off < 256) ? stot[i + off] : 0u;
        __syncthreads(); stot[i] += add; __syncthreads();
    }
    unsigned cum = (i < 255) ? stot[i + 1] : 0u;   // suffix of threads > i
    #pragma unroll
    for (int j = BPT - 1; j >= 0; j--) {
        unsigned nxt = cum;      // suffix(bin+1)
        cum += v[j];             // suffix(bin)
        if (cum >= Kr && nxt < Kr) { sbin = i * BPT + j; srem = Kr - nxt; }
    }
    __syncthreads();
    *rem_out = (sbin >= 0) ? srem : 0u;
    return sbin;
}

// Grid (NOBJ, BB, BPSPLIT): per-(gt,batch) argmax over a prior chunk.
__global__ void k_best_prior(const float* __restrict__ priors,
                             const float* __restrict__ gt,
                             unsigned long long* __restrict__ bp) {
    int n = blockIdx.x, b = blockIdx.y;
    int p0 = blockIdx.z * BPCHUNK;
    int p1 = min(p0 + BPCHUNK, PP);
    const float* t = gt + (b * NOBJ + n) * 4;
    float tx1 = t[0], ty1 = t[1], tx2 = t[2], ty2 = t[3];
    float ta = (tx2 - tx1) * (ty2 - ty1);
    unsigned long long best = 0ull;
    for (int p = p0 + threadIdx.x; p < p1; p += 256) {
        float4 pr = ((const float4*)priors)[p];
        float px1 = pr.x - pr.z * 0.5f, py1 = pr.y - pr.w * 0.5f;
        float px2 = pr.x + pr.z * 0.5f, py2 = pr.y + pr.w * 0.5f;
        float iw = fmaxf(fminf(tx2, px2) - fmaxf(tx1, px1), 0.f);
        float ih = fmaxf(fminf(ty2, py2) - fmaxf(ty1, py1), 0.f);
        float inter = iw * ih;
        float iou = inter / (ta + (px2 - px1) * (py2 - py1) - inter);
        unsigned long long pk = ((unsigned long long)__float_as_uint(iou) << 32)
                              | (unsigned long long)(0xFFFFFFFFu - (unsigned)p);
        if (pk > best) best = pk;
    }
    __shared__ unsigned long long sb[256];
    int tid = threadIdx.x;
    sb[tid] = best; __syncthreads();
    for (int s = 128; s > 0; s >>= 1) {
        if (tid < s && sb[tid + s] > sb[tid]) sb[tid] = sb[tid + s];
        __syncthreads();
    }
    if (tid == 0) atomicMax(&bp[b * NOBJ + n], sb[0]);
}

// Fused match + softmax CE + key. Round-0 proven k_conf load/compute shape
// (64 rows/one-shot block, float4->LDS stage, 4 threads/row) with k_match's
// per-prior work inlined: each row's 4 lanes split the 20-GT IoU argmax
// (5 GTs/lane + shuffle tuple-combine, tie -> lowest n), force-match scan
// (last n wins), ct, and (t==0) loc smooth-L1. conf_t array eliminated:
// negatives are identified downstream by key != 0 (keymap of a finite float
// is never 0).
__global__ void __launch_bounds__(256) k_main(const float* __restrict__ loc_data,
                                              const float* __restrict__ conf_data,
                                              const float* __restrict__ priors,
                                              const float* __restrict__ gt,
                                              const int* __restrict__ labels,
                                              const unsigned long long* __restrict__ bp,
                                              unsigned* __restrict__ key,
                                              float* __restrict__ ce,
                                              float* __restrict__ cnt_f,
                                              int* __restrict__ cnt_i) {
    __shared__ float sx[RPB * CC];       // 20736 B (reused for reduction)
    __shared__ float st2[2][NOBJ][4];    // gt boxes for b0, b0+1
    __shared__ int slab2[2][NOBJ], sbp2[2][NOBJ];
    int tid = threadIdx.x;
    int row0 = blockIdx.x * RPB;
    int b0 = row0 / PP;                  // blocks span at most 2 batches
    int bRowEnd = (b0 + 1) * PP;

    // stage conf rows (coalesced float4; 64 rows == 1296 float4 exactly)
    const float4* g = (const float4*)(conf_data + (size_t)row0 * CC);
    float4* s4 = (float4*)sx;
    #pragma unroll
    for (int i = 0; i < 5; i++) s4[tid + 256 * i] = g[tid + 256 * i];
    if (tid < 16) s4[1280 + tid] = g[1280 + tid];
    // stage gt/labels/bp for b0 and (if in range) b0+1
    if (tid < 2 * NOBJ * 4 && (b0 * NOBJ * 4 + tid) < BB * NOBJ * 4)
        ((float*)st2)[tid] = gt[b0 * NOBJ * 4 + tid];
    if (tid < 2 * NOBJ && (b0 * NOBJ + tid) < BB * NOBJ) {
        ((int*)slab2)[tid] = labels[b0 * NOBJ + tid];
        ((int*)sbp2)[tid] = (int)(0xFFFFFFFFu - (unsigned)bp[b0 * NOBJ + tid]);
    }
    __syncthreads();

    int r = tid >> 2, t = tid & 3;
    int row = row0 + r;
    const float* x = sx + r * CC;

    // ---- softmax partials (proven round-0 math) ----
    float m = (t == 0) ? x[0] : -INFINITY;
    float fg = -INFINITY;
    for (int c = (t == 0) ? 4 : t; c < CC; c += 4) {
        float v = x[c];
        m = fmaxf(m, v);
        fg = fmaxf(fg, v);
    }
    m = fmaxf(m, __shfl_xor(m, 1));
    m = fmaxf(m, __shfl_xor(m, 2));
    fg = fmaxf(fg, __shfl_xor(fg, 1));
    fg = fmaxf(fg, __shfl_xor(fg, 2));

    const float LOG2E = 1.4426950408889634f;
    float e = 0.f;
    for (int c = t; c < CC; c += 4) e += exp2f((x[c] - m) * LOG2E);
    e += __shfl_xor(e, 1);
    e += __shfl_xor(e, 2);

    // ---- fused match: this row's prior vs 20 GTs ----
    int bi = (row >= bRowEnd) ? 1 : 0;
    int p = row - (b0 + bi) * PP;
    float4 pr = ((const float4*)priors)[p];
    float px1 = pr.x - pr.z * 0.5f, py1 = pr.y - pr.w * 0.5f;
    float px2 = pr.x + pr.z * 0.5f, py2 = pr.y + pr.w * 0.5f;
    float pa = (px2 - px1) * (py2 - py1);
    float best = -1.f; int bn = t;
    #pragma unroll
    for (int j = 0; j < 5; j++) {
        int n = t + 4 * j;
        float tx1 = st2[bi][n][0], ty1 = st2[bi][n][1];
        float tx2 = st2[bi][n][2], ty2 = st2[bi][n][3];
        float iw = fmaxf(fminf(tx2, px2) - fmaxf(tx1, px1), 0.f);
        float ih = fmaxf(fminf(ty2, py2) - fmaxf(ty1, py1), 0.f);
        float inter = iw * ih;
        float iou = inter / ((tx2 - tx1) * (ty2 - ty1) + pa - inter);
        if (iou > best) { best = iou; bn = n; }   // tie -> first n (in-lane)
    }
    #pragma unroll
    for (int off = 1; off <= 2; off <<= 1) {      // tie -> lowest n (cross-lane)
        float ob = __shfl_xor(best, off);
        int obn = __shfl_xor(bn, off);
        if (ob > best || (ob == best && obn < bn)) { best = ob; bn = obn; }
    }
    int fm = -1;
    #pragma unroll
    for (int j = 0; j < 5; j++) {
        int n = t + 4 * j;
        if (sbp2[bi][n] == p) fm = n;             // ascending: last in-lane wins
    }
    fm = max(fm, __shfl_xor(fm, 1));
    fm = max(fm, __shfl_xor(fm, 2));              // last (max n) wins overall
    float ov = best;
    if (fm >= 0) { bn = fm; ov = 2.0f; }
    int ct = slab2[bi][bn];
    if (ov < 0.5f) ct = -1;
    if (ov < 0.4f) ct = 0;

    // ---- epilogue (t==0): CE, key, loc loss ----
    float s_l1 = 0.f; int is_pos = 0;
    if (t == 0) {
        float lse = m + log2f(e) * 0.6931471805599453f;
        int ctc = min(max(ct, 0), CC - 1);
        float cev = lse - x[ctc];
        ce[row] = cev;
        key[row] = (ct == 0) ? keymap(fg) : 0u;
        if (ct > 0) {
            atomicAdd(&cnt_f[2], cev);
            is_pos = 1;
            float mx1 = st2[bi][bn][0], my1 = st2[bi][bn][1];
            float mx2 = st2[bi][bn][2], my2 = st2[bi][bn][3];
            float gcx = ((mx1 + mx2) * 0.5f - pr.x) / (0.1f * pr.z);
            float gcy = ((my1 + my2) * 0.5f - pr.y) / (0.1f * pr.w);
            float gw = logf((mx2 - mx1) / pr.z) / 0.2f;
            float gh = logf((my2 - my1) / pr.w) / 0.2f;
            float4 ld = ((const float4*)loc_data)[row];
            s_l1 = smooth_l1(ld.x - gcx) + smooth_l1(ld.y - gcy) +
                   smooth_l1(ld.z - gw) + smooth_l1(ld.w - gh);
        }
    }
    // block reduce s_l1 / is_pos, reusing sx (all sx reads are done)
    __syncthreads();
    float* rs = sx; int* rc = (int*)(sx + 256);
    rs[tid] = s_l1; rc[tid] = is_pos; __syncthreads();
    for (int s = 128; s > 0; s >>= 1) {
        if (tid < s) { rs[tid] += rs[tid + s]; rc[tid] += rc[tid + s]; }
        __syncthreads();
    }
    if (tid == 0) {
        if (rs[0] != 0.f) atomicAdd(&cnt_f[1], rs[0]);
        if (rc[0])        atomicAdd(&cnt_i[0], rc[0]);
    }
}

// Three radix-select phases (bits 31:21, 20:10, 9:0) + negative-CE sum +
// final losses in ONE kernel. Cross-block sync: relaxed agent atomics only
// (no cache-maintenance ops — round-5 lesson), writer ordering by vmcnt(0)
// completion, reader ordering by data dependence. SELBLK=128 one-wave-grid
// keeps spin/done-counter traffic minimal; co-residency trivially guaranteed.
// Negative candidates identified by key != 0 (== conf_t==0).
__global__ void __launch_bounds__(256) k_sel(const unsigned* __restrict__ key,
                                             const float* __restrict__ ce,
                                             int* __restrict__ cnt_i,
                                             float* __restrict__ cnt_f,
                                             unsigned* __restrict__ hA,
                                             unsigned* __restrict__ hB,
                                             unsigned* __restrict__ hC,
                                             float* __restrict__ out) {
    __shared__ unsigned lh[2048];
    __shared__ int amLast;
    int tid = threadIdx.x;
    const uint4* k4 = (const uint4*)key;
    int n4 = ROWS / 4;

    // ---- phase A: bits 31:21 ----
    for (int j = tid; j < 2048; j += 256) lh[j] = 0;
    __syncthreads();
    for (int r = blockIdx.x * 256 + tid; r < n4; r += gridDim.x * 256) {
        uint4 k = k4[r];
        if (k.x) atomicAdd(&lh[k.x >> 21], 1u);
        if (k.y) atomicAdd(&lh[k.y >> 21], 1u);
        if (k.z) atomicAdd(&lh[k.z >> 21], 1u);
        if (k.w) atomicAdd(&lh[k.w >> 21], 1u);
    }
    __syncthreads();
    {
        unsigned* hmy = hA + (blockIdx.x & 3) * 2048;
        for (int j = tid; j < 2048; j += 256)
            if (lh[j]) atomicAdd(&hmy[j], lh[j]);
    }
    VMEM_DRAIN();
    if (tid == 0)
        amLast = (__hip_atomic_fetch_add((unsigned*)&cnt_i[6], 1u,
                   __ATOMIC_RELAXED, SCOPE_AGENT) == (unsigned)(gridDim.x - 1));
    __syncthreads();
    if (amLast) {
        unsigned Kr = 3u * (unsigned)aload_i(&cnt_i[0]);
        if (Kr == 0) {           // no positives: select no negatives
            if (tid == 0) {
                astore_i(&cnt_i[10], (int)0xFFFFFFFFu); astore_i(&cnt_i[11], 0);
                astore_i(&cnt_i[7], 1);
                VMEM_DRAIN();
                astore_i(&cnt_i[20], 1);  // flagA
                astore_i(&cnt_i[21], 1);  // flagD (B/C skipped)
            }
        } else {
            unsigned rem; int bin = scan_bins<2048, 4>(hA, Kr, &rem);
            if (tid == 0) {
                if (bin < 0) {   // total < Kr: select all candidates
                    astore_i(&cnt_i[10], 0); astore_i(&cnt_i[11], 0);
                    astore_i(&cnt_i[7], 1);
                    VMEM_DRAIN();
                    astore_i(&cnt_i[20], 1);
                    astore_i(&cnt_i[21], 1);
                } else {
                    astore_i(&cnt_i[8], bin);
                    astore_i(&cnt_i[9], (int)rem);
                    VMEM_DRAIN();
                    astore_i(&cnt_i[20], 1);
                }
            }
        }
    }
    if (tid == 0) {   // relaxed spin: no cache-invalidate per iteration
        while (aload_i(&cnt_i[20]) == 0) __builtin_amdgcn_s_sleep(8);
    }
    __syncthreads();
    int skip = aload_i(&cnt_i[7]);

    if (!skip) {
        unsigned prefixA = (unsigned)aload_i(&cnt_i[8]);
        unsigned KrB = (unsigned)aload_i(&cnt_i[9]);

        // ---- phase B: bits 20:10 within prefixA ----
        for (int j = tid; j < 2048; j += 256) lh[j] = 0;
        __syncthreads();
        for (int r = blockIdx.x * 256 + tid; r < n4; r += gridDim.x * 256) {
            uint4 k = k4[r];
            if (k.x && (k.x >> 21) == prefixA) atomicAdd(&lh[(k.x >> 10) & 0x7FFu], 1u);
            if (k.y && (k.y >> 21) == prefixA) atomicAdd(&lh[(k.y >> 10) & 0x7FFu], 1u);
            if (k.z && (k.z >> 21) == prefixA) atomicAdd(&lh[(k.z >> 10) & 0x7FFu], 1u);
            if (k.w && (k.w >> 21) == prefixA) atomicAdd(&lh[(k.w >> 10) & 0x7FFu], 1u);
        }
        __syncthreads();
        {
            unsigned* hmy = hB + (blockIdx.x & 3) * 2048;
            for (int j = tid; j < 2048; j += 256)
                if (lh[j]) atomicAdd(&hmy[j], lh[j]);
        }
        VMEM_DRAIN();
        if (tid == 0)
            amLast = (__hip_atomic_fetch_add((unsigned*)&cnt_i[12], 1u,
                       __ATOMIC_RELAXED, SCOPE_AGENT) == (unsigned)(gridDim.x - 1));
        __syncthreads();
        if (amLast) {
            unsigned rem; int bin = scan_bins<2048, 4>(hB, KrB, &rem);
            if (bin < 0) { bin = 0; rem = 0; }   // defensive (cannot happen)
            if (tid == 0) {
                astore_i(&cnt_i[15], (int)((prefixA << 11) | (unsigned)bin));
                astore_i(&cnt_i[16], (int)rem);
                VMEM_DRAIN();
                astore_i(&cnt_i[14], 1);  // flagB
            }
        }
        if (tid == 0) {
            while (aload_i(&cnt_i[14]) == 0) __builtin_amdgcn_s_sleep(8);
        }
        __syncthreads();
        unsigned prefixAB = (unsigned)aload_i(&cnt_i[15]);
        unsigned KrC = (unsigned)aload_i(&cnt_i[16]);

        // ---- phase C: bits 9:0 within prefixAB ----
        for (int j = tid; j < 1024; j += 256) lh[j] = 0;
        __syncthreads();
        for (int r = blockIdx.x * 256 + tid; r < n4; r += gridDim.x * 256) {
            uint4 k = k4[r];
            if (k.x && (k.x >> 10) == prefixAB) atomicAdd(&lh[k.x & 0x3FFu], 1u);
            if (k.y && (k.y >> 10) == prefixAB) atomicAdd(&lh[k.y & 0x3FFu], 1u);
            if (k.z && (k.z >> 10) == prefixAB) atomicAdd(&lh[k.z & 0x3FFu], 1u);
            if (k.w && (k.w >> 10) == prefixAB) atomicAdd(&lh[k.w & 0x3FFu], 1u);
        }
        __syncthreads();
        {
            unsigned* hmy = hC + (blockIdx.x & 3) * 1024;
            for (int j = tid; j < 1024; j += 256)
                if (lh[j]) atomicAdd(&hmy[j], lh[j]);
        }
        VMEM_DRAIN();
        if (tid == 0)
            amLast = (__hip_atomic_fetch_add((unsigned*)&cnt_i[17], 1u,
                       __ATOMIC_RELAXED, SCOPE_AGENT) == (unsigned)(gridDim.x - 1));
        __syncthreads();
        if (amLast) {
            unsigned rem; int bin = scan_bins<1024, 4>(hC, KrC, &rem);
            if (bin < 0) { bin = 0; rem = 0; }   // defensive
            if (tid == 0) {
                astore_i(&cnt_i[10], (int)((prefixAB << 10) | (unsigned)bin));
                astore_i(&cnt_i[11], (int)rem);
                VMEM_DRAIN();
                astore_i(&cnt_i[21], 1);  // flagD
            }
        }
    }

    // ---- phase D: sum CE over selected negatives + final losses ----
    if (tid == 0) {
        while (aload_i(&cnt_i[21]) == 0) __builtin_amdgcn_s_sleep(8);
    }
    __syncthreads();
    unsigned T = (unsigned)aload_i(&cnt_i[10]);
    int eqS = aload_i(&cnt_i[11]);
    float s = 0.f; int c = 0;
    for (int r = blockIdx.x * 256 + tid; r < n4; r += gridDim.x * 256) {
        uint4 k = k4[r];
        #define DO_ONE(comp, idx) { \
            unsigned kk = k.comp; \
            if (kk) { \
                bool selr = false; \
                if (kk > T) selr = true; \
                else if (kk == T) { int slot = atomicAdd(&cnt_i[5], 1); selr = slot < eqS; } \
                if (selr) { s += ce[4 * r + idx]; c++; } \
            } }
        DO_ONE(x, 0) DO_ONE(y, 1) DO_ONE(z, 2) DO_ONE(w, 3)
        #undef DO_ONE
    }
    __shared__ float rs[256]; __shared__ int rc[256];
    rs[tid] = s; rc[tid] = c; __syncthreads();
    for (int st = 128; st > 0; st >>= 1) {
        if (tid < st) { rs[tid] += rs[tid + st]; rc[tid] += rc[tid + st]; }
        __syncthreads();
    }
    if (tid == 0) {
        if (rs[0] != 0.f) atomicAdd(&cnt_f[3], rs[0]);
        if (rc[0])        atomicAdd(&cnt_i[4], rc[0]);
    }
    VMEM_DRAIN();
    if (tid == 0 &&
        __hip_atomic_fetch_add((unsigned*)&cnt_i[13], 1u,
            __ATOMIC_RELAXED, SCOPE_AGENT) == (unsigned)(gridDim.x - 1)) {
        int np = aload_i(&cnt_i[0]);
        int nn = aload_i(&cnt_i[4]);
        float f1 = aload_f(&cnt_f[1]);
        float f2 = aload_f(&cnt_f[2]);
        float f3 = aload_f(&cnt_f[3]);
        out[0] = f1 / (float)max(np, 1);
        out[1] = (f2 + f3) / (float)max(np + nn, 1);
    }
}

extern "C" void kernel_launch(void* const* d_in, const int* in_sizes, int n_in,
                              void* d_out, int out_size, void* d_ws, size_t ws_size,
                              hipStream_t stream) {
    const float* loc    = (const float*)d_in[0];
    const float* conf   = (const float*)d_in[1];
    const float* priors = (const float*)d_in[2];
    const float* gt     = (const float*)d_in[3];
    const int*   labels = (const int*)d_in[4];
    float* out = (float*)d_out;
    int*      wi = (int*)d_ws;
    float*    wf = (float*)d_ws;
    unsigned* wu = (unsigned*)d_ws;
    unsigned long long* wbp = (unsigned long long*)(wi + W_BP);

    hipMemsetAsync(d_ws, 0, MEMSET_BYTES, stream);  // counters + bp + hists
    k_best_prior<<<dim3(NOBJ, BB, BPSPLIT), 256, 0, stream>>>(priors, gt, wbp);
    k_main<<<ROWS / RPB, 256, 0, stream>>>(loc, conf, priors, gt, labels, wbp,
                                           wu + W_KEY, wf + W_CE, wf, wi);
    k_sel<<<SELBLK, 256, 0, stream>>>(wu + W_KEY, wf + W_CE, wi, wf,
                                      wu + W_HA, wu + W_HB, wu + W_HC, out);
}

// Round 8
// 470.056 us; speedup vs baseline: 1.1332x; 1.1332x over previous
//
#include <hip/hip_runtime.h>
#include <math.h>

#define BB 8
#define PP 57744
#define NOBJ 20
#define CC 81
#define ROWS (BB*PP)
#define RPB 64        // rows per block in k_conf
#define CONFBLK (ROWS / RPB)       // 7218 total conf blocks
#define CONFHALF (CONFBLK / 2)     // 3609 per launch (split for rocprof attribution)
#define BPSPLIT 16
#define BPCHUNK ((PP + BPSPLIT - 1) / BPSPLIT)   // 3609

// ws layout in 4-byte units
// cnt: [0]=num_pos [1]=sl1_sum [2]=pos_ce [3]=neg_ce [4]=neg_cnt [5]=eqCtr
//      [8]=prefix [9]=Kr [10]=T [11]=eqSlots
#define W_CNT  0                        // 64 words
#define W_HIST 64                       // 4 passes x 8 copies x 256 bins = 8192
#define W_BP   (64 + 8192)              // 8256: 160 u64 (byte 33024, 8-aligned)
#define W_CONF (W_BP + 320)             // 8576: ROWS ints
#define W_KEY  (W_CONF + ROWS)
#define W_CE   (W_KEY + ROWS)
#define MEMSET_BYTES (W_CONF * 4)       // 34304 B: counters + hists + bp

__device__ __forceinline__ unsigned keymap(float f) {
    unsigned u = __float_as_uint(f);
    return (u & 0x80000000u) ? ~u : (u | 0x80000000u);
}

__device__ __forceinline__ float smooth_l1(float d) {
    float a = fabsf(d);
    return a < 1.f ? 0.5f * d * d : a - 0.5f;
}

// Grid (NOBJ, BB, BPSPLIT): per-(gt,batch) argmax over a prior chunk, packed
// (iou_bits<<32)|(~p) so u64 max == (max iou, lowest prior idx).
__global__ void k_best_prior(const float* __restrict__ priors,
                             const float* __restrict__ gt,
                             unsigned long long* __restrict__ bp) {
    int n = blockIdx.x, b = blockIdx.y;
    int p0 = blockIdx.z * BPCHUNK;
    int p1 = min(p0 + BPCHUNK, PP);
    const float* t = gt + (b * NOBJ + n) * 4;
    float tx1 = t[0], ty1 = t[1], tx2 = t[2], ty2 = t[3];
    float ta = (tx2 - tx1) * (ty2 - ty1);
    unsigned long long best = 0ull;
    for (int p = p0 + threadIdx.x; p < p1; p += 256) {
        float4 pr = ((const float4*)priors)[p];
        float px1 = pr.x - pr.z * 0.5f, py1 = pr.y - pr.w * 0.5f;
        float px2 = pr.x + pr.z * 0.5f, py2 = pr.y + pr.w * 0.5f;
        float iw = fmaxf(fminf(tx2, px2) - fmaxf(tx1, px1), 0.f);
        float ih = fmaxf(fminf(ty2, py2) - fmaxf(ty1, py1), 0.f);
        float inter = iw * ih;
        float iou = inter / (ta + (px2 - px1) * (py2 - py1) - inter);
        unsigned long long pk = ((unsigned long long)__float_as_uint(iou) << 32)
                              | (unsigned long long)(0xFFFFFFFFu - (unsigned)p);
        if (pk > best) best = pk;
    }
    __shared__ unsigned long long sb[256];
    int tid = threadIdx.x;
    sb[tid] = best; __syncthreads();
    for (int s = 128; s > 0; s >>= 1) {
        if (tid < s && sb[tid + s] > sb[tid]) sb[tid] = sb[tid + s];
        __syncthreads();
    }
    if (tid == 0) atomicMax(&bp[b * NOBJ + n], sb[0]);
}

// Per prior: best truth (argmax over 20, tie->first), force-match (last gt wins),
// conf_t, and smooth-L1 loc loss for positives.
__global__ void k_match(const float* __restrict__ loc_data,
                        const float* __restrict__ priors,
                        const float* __restrict__ gt,
                        const int* __restrict__ labels,
                        const unsigned long long* __restrict__ bp,
                        int* __restrict__ conf_t,
                        float* __restrict__ cnt_f,
                        int* __restrict__ cnt_i) {
    int b = blockIdx.y;
    int tid = threadIdx.x;
    int p = blockIdx.x * 256 + tid;
    __shared__ float st[NOBJ][4];
    __shared__ int slab[NOBJ], sbp[NOBJ];
    if (tid < NOBJ * 4) ((float*)st)[tid] = gt[b * NOBJ * 4 + tid];
    if (tid < NOBJ) {
        slab[tid] = labels[b * NOBJ + tid];
        sbp[tid] = (int)(0xFFFFFFFFu - (unsigned)bp[b * NOBJ + tid]);
    }
    __syncthreads();
    float s_l1 = 0.f; int is_pos = 0;
    if (p < PP) {
        float4 pr = ((const float4*)priors)[p];
        float px1 = pr.x - pr.z * 0.5f, py1 = pr.y - pr.w * 0.5f;
        float px2 = pr.x + pr.z * 0.5f, py2 = pr.y + pr.w * 0.5f;
        float pa = (px2 - px1) * (py2 - py1);
        float best = -1.f; int bn = 0;
        for (int n = 0; n < NOBJ; n++) {
            float tx1 = st[n][0], ty1 = st[n][1], tx2 = st[n][2], ty2 = st[n][3];
            float iw = fmaxf(fminf(tx2, px2) - fmaxf(tx1, px1), 0.f);
            float ih = fmaxf(fminf(ty2, py2) - fmaxf(ty1, py1), 0.f);
            float inter = iw * ih;
            float iou = inter / ((tx2 - tx1) * (ty2 - ty1) + pa - inter);
            if (iou > best) { best = iou; bn = n; }  // tie -> first n
        }
        float ov = best;
        for (int n = 0; n < NOBJ; n++)
            if (sbp[n] == p) { bn = n; ov = 2.0f; }  // last n wins
        int conf = slab[bn];
        if (ov < 0.5f) conf = -1;
        if (ov < 0.4f) conf = 0;
        conf_t[b * PP + p] = conf;
        if (conf > 0) {
            is_pos = 1;
            float mx1 = st[bn][0], my1 = st[bn][1], mx2 = st[bn][2], my2 = st[bn][3];
            float gcx = ((mx1 + mx2) * 0.5f - pr.x) / (0.1f * pr.z);
            float gcy = ((my1 + my2) * 0.5f - pr.y) / (0.1f * pr.w);
            float gw = logf((mx2 - mx1) / pr.z) / 0.2f;
            float gh = logf((my2 - my1) / pr.w) / 0.2f;
            float4 ld = ((const float4*)loc_data)[b * PP + p];
            s_l1 = smooth_l1(ld.x - gcx) + smooth_l1(ld.y - gcy) +
                   smooth_l1(ld.z - gw) + smooth_l1(ld.w - gh);
        }
    }
    __shared__ float rs[256]; __shared__ int rc[256];
    rs[tid] = s_l1; rc[tid] = is_pos; __syncthreads();
    for (int s = 128; s > 0; s >>= 1) {
        if (tid < s) { rs[tid] += rs[tid + s]; rc[tid] += rc[tid + s]; }
        __syncthreads();
    }
    if (tid == 0) {
        if (rs[0] != 0.f) atomicAdd(&cnt_f[1], rs[0]);
        if (rc[0])        atomicAdd(&cnt_i[0], rc[0]);
    }
}

// Round-0 proven structure (159us full-size): 64 rows per one-shot block
// staged via coalesced float4 -> LDS; 4 threads/row serial scan with native
// exp2/log2. Launched TWICE at half grid (baseBlk 0 / CONFHALF) so each
// instance is ~80us — lowers the rocprof top-5 cutoff to expose tail kernels.
__global__ void __launch_bounds__(256) k_conf(const float* __restrict__ conf_data,
                                              const int* __restrict__ conf_t,
                                              unsigned* __restrict__ key,
                                              float* __restrict__ ce,
                                              float* __restrict__ cnt_f,
                                              int baseBlk) {
    __shared__ float sx[RPB * CC];   // 20736 B
    int tid = threadIdx.x;
    int blk = blockIdx.x + baseBlk;
    const float4* g = (const float4*)(conf_data + (size_t)blk * (RPB * CC));
    float4* s4 = (float4*)sx;
    #pragma unroll
    for (int i = 0; i < 5; i++) s4[tid + 256 * i] = g[tid + 256 * i];
    if (tid < (RPB * CC / 4) - 1280) s4[1280 + tid] = g[1280 + tid];
    __syncthreads();

    int r = tid >> 2, t = tid & 3;
    int row = blk * RPB + r;
    const float* x = sx + r * CC;

    float m = (t == 0) ? x[0] : -INFINITY;
    float fg = -INFINITY;
    for (int c = (t == 0) ? 4 : t; c < CC; c += 4) {
        float v = x[c];
        m = fmaxf(m, v);
        fg = fmaxf(fg, v);
    }
    m = fmaxf(m, __shfl_xor(m, 1));
    m = fmaxf(m, __shfl_xor(m, 2));
    fg = fmaxf(fg, __shfl_xor(fg, 1));
    fg = fmaxf(fg, __shfl_xor(fg, 2));

    const float LOG2E = 1.4426950408889634f;
    float e = 0.f;
    for (int c = t; c < CC; c += 4) e += exp2f((x[c] - m) * LOG2E);
    e += __shfl_xor(e, 1);
    e += __shfl_xor(e, 2);

    if (t == 0) {
        float lse = m + log2f(e) * 0.6931471805599453f;
        int ct = conf_t[row];
        int ctc = min(max(ct, 0), CC - 1);
        float cev = lse - x[ctc];
        ce[row] = cev;
        key[row] = (ct == 0) ? keymap(fg) : 0u;
        if (ct > 0) atomicAdd(&cnt_f[2], cev);
    }
}

// Radix-select pass s (8-bit digits, MSB first) histogram. LDS-privatized;
// flush spread over 8 global copies (blockIdx&7) so hot bins (pass 0's
// key>>24 concentrates) don't serialize 512 blocks on one cache line.
__global__ void k_hist(const unsigned* __restrict__ key,
                       unsigned* __restrict__ hist,
                       const int* __restrict__ cnt, int s) {
    __shared__ unsigned lh[256];
    int tid = threadIdx.x;
    lh[tid] = 0; __syncthreads();
    unsigned prefix = (s == 0) ? 0u : (unsigned)cnt[8];
    int shift = 24 - 8 * s;
    for (int r = blockIdx.x * 256 + tid; r < ROWS; r += gridDim.x * 256) {
        unsigned k = key[r];
        if (s == 0 || (k >> (shift + 8)) == prefix)
            atomicAdd(&lh[(k >> shift) & 0xffu], 1u);
    }
    __syncthreads();
    if (lh[tid])
        atomicAdd(&hist[(s * 8 + (blockIdx.x & 7)) * 256 + tid], lh[tid]);
}

// Pick the digit where the descending cumulative count crosses Kr.
__global__ void k_scan(const unsigned* __restrict__ hist, int* __restrict__ cnt, int s) {
    __shared__ unsigned sd[256];
    int i = threadIdx.x;
    unsigned v = 0;
    #pragma unroll
    for (int c = 0; c < 8; c++) v += hist[(s * 8 + c) * 256 + i];
    sd[i] = v;
    __syncthreads();
    for (int off = 1; off < 256; off <<= 1) {
        unsigned add = (i + off < 256) ? sd[i + off] : 0u;
        __syncthreads();
        sd[i] += add;
        __syncthreads();
    }
    unsigned Kr, prefix;
    if (s == 0) { Kr = 3u * (unsigned)cnt[0]; prefix = 0u; }
    else        { prefix = (unsigned)cnt[8]; Kr = (unsigned)cnt[9]; }
    unsigned cum = sd[i];
    unsigned upper = (i < 255) ? sd[i + 1] : 0u;
    bool sel = (upper < Kr) && (cum >= Kr || i == 0);
    if (sel) {
        unsigned np = (prefix << 8) | (unsigned)i;
        unsigned nKr = Kr - upper;
        if (s < 3) { cnt[8] = (int)np; cnt[9] = (int)nKr; }
        else       { cnt[10] = (int)np; cnt[11] = (int)nKr; }
    }
}

// Sum CE over selected negatives (key > T, or == T up to eqSlots).
__global__ void k_negsum(const unsigned* __restrict__ key,
                         const float* __restrict__ ce,
                         const int* __restrict__ conf_t,
                         int* __restrict__ cnt_i,
                         float* __restrict__ cnt_f) {
    int tid = threadIdx.x;
    int r = blockIdx.x * 256 + tid;
    float s = 0.f; int c = 0;
    unsigned T = (unsigned)cnt_i[10];
    int eqS = cnt_i[11];
    if (r < ROWS && conf_t[r] == 0) {
        unsigned k = key[r];
        bool sel = false;
        if (k > T) sel = true;
        else if (k == T) { int slot = atomicAdd(&cnt_i[5], 1); sel = slot < eqS; }
        if (sel) { s = ce[r]; c = 1; }
    }
    __shared__ float rs[256]; __shared__ int rc[256];
    rs[tid] = s; rc[tid] = c; __syncthreads();
    for (int st = 128; st > 0; st >>= 1) {
        if (tid < st) { rs[tid] += rs[tid + st]; rc[tid] += rc[tid + st]; }
        __syncthreads();
    }
    if (tid == 0) {
        if (rs[0] != 0.f) atomicAdd(&cnt_f[3], rs[0]);
        if (rc[0])        atomicAdd(&cnt_i[4], rc[0]);
    }
}

__global__ void k_final(const int* __restrict__ cnt_i,
                        const float* __restrict__ cnt_f,
                        float* __restrict__ out) {
    int np = cnt_i[0], nn = cnt_i[4];
    out[0] = cnt_f[1] / (float)max(np, 1);
    out[1] = (cnt_f[2] + cnt_f[3]) / (float)max(np + nn, 1);
}

extern "C" void kernel_launch(void* const* d_in, const int* in_sizes, int n_in,
                              void* d_out, int out_size, void* d_ws, size_t ws_size,
                              hipStream_t stream) {
    const float* loc    = (const float*)d_in[0];
    const float* conf   = (const float*)d_in[1];
    const float* priors = (const float*)d_in[2];
    const float* gt     = (const float*)d_in[3];
    const int*   labels = (const int*)d_in[4];
    float* out = (float*)d_out;
    int*      wi = (int*)d_ws;
    float*    wf = (float*)d_ws;
    unsigned* wu = (unsigned*)d_ws;
    unsigned long long* wbp = (unsigned long long*)(wi + W_BP);

    hipMemsetAsync(d_ws, 0, MEMSET_BYTES, stream);  // counters + hists + bp
    k_best_prior<<<dim3(NOBJ, BB, BPSPLIT), 256, 0, stream>>>(priors, gt, wbp);
    k_match<<<dim3((PP + 255) / 256, BB), 256, 0, stream>>>(
        loc, priors, gt, labels, wbp, wi + W_CONF, wf, wi);
    k_conf<<<CONFHALF, 256, 0, stream>>>(conf, wi + W_CONF, wu + W_KEY,
                                         wf + W_CE, wf, 0);
    k_conf<<<CONFHALF, 256, 0, stream>>>(conf, wi + W_CONF, wu + W_KEY,
                                         wf + W_CE, wf, CONFHALF);
    for (int s = 0; s < 4; s++) {
        k_hist<<<512, 256, 0, stream>>>(wu + W_KEY, wu + W_HIST, wi, s);
        k_scan<<<1, 256, 0, stream>>>(wu + W_HIST, wi, s);
    }
    k_negsum<<<(ROWS + 255) / 256, 256, 0, stream>>>(
        wu + W_KEY, wf + W_CE, wi + W_CONF, wi, wf);
    k_final<<<1, 1, 0, stream>>>(wi, wf, out);
}